// Round 1
// baseline (915.965 us; speedup 1.0000x reference)
//
#include <hip/hip_runtime.h>
#include <hip/hip_bf16.h>

#define NHEAD 34
#define HDIM  100
#define NNODE 200
#define NBATCH 32
#define EPSV 1e-20f

// ---------------------------------------------------------------------------
// dvec0[b,f,n] = start[b,n] * uni[b,f]
__global__ void dvec0_calc(const float* __restrict__ start, const float* __restrict__ uni,
                           float* __restrict__ dvec0) {
    int idx = blockIdx.x * 256 + threadIdx.x;
    if (idx >= NBATCH * NHEAD * NNODE) return;
    int b = idx / (NHEAD * NNODE);
    int r = idx % (NHEAD * NNODE);
    int f = r / NNODE;
    int n = r % NNODE;
    dvec0[idx] = start[b * NNODE + n] * uni[b * NHEAD + f];
}

// ---------------------------------------------------------------------------
// Generic per-(b,head) GEMM: Dst[b,f,n,o] = u * sum_i S[n,i] * W[f][i,o]
//   S = src + (src_head ? (b*gridDim.x+f) : b)*20000, optionally row-scaled.
// Used for: Zh0 (src=X, rowscale=start, uni=uni)
//           Zh1 (src=Zin1, rowscale=null, uni=uni)
//           out0 (grid.x=1, src=Zsum0, rowscale=rs0, uni=null, W=Wi1)
__global__ __launch_bounds__(256) void zh_gemm(
    const float* __restrict__ src, const float* __restrict__ wbase,
    const float* __restrict__ uni, const float* __restrict__ rowscale,
    float* __restrict__ dst, int src_head)
{
    int f = blockIdx.x, b = blockIdx.y;
    int NHg = gridDim.x;
    const float* W = wbase + (size_t)f * 10000;
    const float* S = src + (size_t)(src_head ? (b * NHg + f) : b) * 20000;
    float* Dst = dst + (size_t)(b * NHg + f) * 20000;

    __shared__ __align__(16) float wl[10000];   // W[f]: [i][o], 40KB
    __shared__ __align__(16) float xl[5000];    // 50 input rows, 20KB

    int tid = threadIdx.x;
    for (int idx = tid; idx < 10000; idx += 256) wl[idx] = W[idx];
    float u = uni ? uni[b * NHEAD + f] : 1.0f;

    int q  = tid % 25;   // o-quad: o = 4q..4q+3
    int ty = tid / 25;   // 0..9 active (tid<250)

    for (int c = 0; c < 4; c++) {           // 4 chunks of 50 rows
        __syncthreads();
        int base = c * 5000;
        for (int idx = tid; idx < 5000; idx += 256) {
            int row = idx / 100;
            float sc = rowscale ? rowscale[b * NNODE + c * 50 + row] : 1.0f;
            xl[idx] = S[base + idx] * sc;
        }
        __syncthreads();
        if (ty < 10) {
            float4 acc[5];
            #pragma unroll
            for (int r = 0; r < 5; r++) acc[r] = make_float4(0.f, 0.f, 0.f, 0.f);
            #pragma unroll 2
            for (int i = 0; i < 100; i++) {
                float4 w4 = *(const float4*)&wl[i * 100 + q * 4];
                #pragma unroll
                for (int r = 0; r < 5; r++) {
                    float x = xl[(ty + 10 * r) * 100 + i];
                    acc[r].x += x * w4.x; acc[r].y += x * w4.y;
                    acc[r].z += x * w4.z; acc[r].w += x * w4.w;
                }
            }
            #pragma unroll
            for (int r = 0; r < 5; r++) {
                int n = c * 50 + ty + 10 * r;
                float4 o4 = make_float4(acc[r].x * u, acc[r].y * u, acc[r].z * u, acc[r].w * u);
                *(float4*)&Dst[n * 100 + q * 4] = o4;
            }
        }
    }
}

// ---------------------------------------------------------------------------
// Sparse A-multiply + D-path, one block per (b,f):
//   Zout[b,f,m,o] = sum_n A[b,f,m,n] * Zin[b,f,n,o]
//   Dh[b,f,m]     = sum_n A[b,f,m,n] * dvec[b,f,n]
// A is 0/1 @5% — wave ballots nonzeros and gathers only those Z rows.
__global__ __launch_bounds__(512) void a_spmm(
    const float* __restrict__ A, const float* __restrict__ Zin,
    const float* __restrict__ dvec, float* __restrict__ Zout, float* __restrict__ Dh)
{
    int f = blockIdx.x, b = blockIdx.y;
    size_t bf = (size_t)b * NHEAD + f;
    __shared__ float dl[NNODE];
    int tid = threadIdx.x;
    if (tid < NNODE) dl[tid] = dvec[bf * NNODE + tid];
    __syncthreads();

    int wave = tid >> 6, lane = tid & 63;
    const float* Ab = A + bf * (NNODE * NNODE);
    const float* Zb = Zin + bf * (NNODE * HDIM);
    float* Zob = Zout + bf * (NNODE * HDIM);
    int o2 = 2 * lane;
    bool oact = (lane < 50);

    for (int m = wave; m < NNODE; m += 8) {
        const float* Ar = Ab + m * NNODE;
        float a0 = Ar[lane];
        float a1 = Ar[64 + lane];
        float a2 = Ar[128 + lane];
        float a3 = (lane < 8) ? Ar[192 + lane] : 0.0f;
        float accx = 0.f, accy = 0.f, accd = 0.f;
        #pragma unroll
        for (int ch = 0; ch < 4; ch++) {
            float ac = (ch == 0) ? a0 : (ch == 1) ? a1 : (ch == 2) ? a2 : a3;
            unsigned long long mask = __ballot(ac != 0.0f);
            while (mask) {
                int l = __ffsll(mask) - 1;
                mask &= (mask - 1);
                int n = ch * 64 + l;
                float av = __shfl(ac, l);
                accd += av * dl[n];
                if (oact) {
                    float2 zv = *(const float2*)&Zb[n * 100 + o2];
                    accx += av * zv.x;
                    accy += av * zv.y;
                }
            }
        }
        if (oact) {
            float2 o = make_float2(accx, accy);
            *(float2*)&Zob[m * 100 + o2] = o;
        }
        if (lane == 0) Dh[bf * NNODE + m] = accd;
    }
}

// ---------------------------------------------------------------------------
// rs[b,m] = end[b,m] / (end[b,m] * sum_f Dh[b,f,m] + EPS)
__global__ void dsum_rs(const float* __restrict__ Dh, const float* __restrict__ endat,
                        float* __restrict__ rs) {
    int idx = blockIdx.x * 256 + threadIdx.x;
    if (idx >= NBATCH * NNODE) return;
    int b = idx / NNODE, m = idx % NNODE;
    float s = 0.f;
    #pragma unroll
    for (int f = 0; f < NHEAD; f++) s += Dh[((size_t)b * NHEAD + f) * NNODE + m];
    float e = endat[idx];
    rs[idx] = e / (e * s + EPSV);
}

// ---------------------------------------------------------------------------
// dvec1[b,g,n] = uni[b,g] * sum_f Dh0[b,f,n] * trans[b,f,g]
__global__ void dmix(const float* __restrict__ Dh0, const float* __restrict__ trans,
                     const float* __restrict__ uni, float* __restrict__ dvec1) {
    int b = blockIdx.x;
    __shared__ float tl[NHEAD * NHEAD];
    for (int idx = threadIdx.x; idx < NHEAD * NHEAD; idx += 256) tl[idx] = trans[b * NHEAD * NHEAD + idx];
    __syncthreads();
    int n = threadIdx.x;
    if (n < NNODE) {
        float dh[NHEAD];
        #pragma unroll
        for (int f = 0; f < NHEAD; f++) dh[f] = Dh0[((size_t)b * NHEAD + f) * NNODE + n];
        #pragma unroll
        for (int g = 0; g < NHEAD; g++) {
            float acc = 0.f;
            #pragma unroll
            for (int f = 0; f < NHEAD; f++) acc += dh[f] * tl[f * NHEAD + g];
            dvec1[((size_t)b * NHEAD + g) * NNODE + n] = uni[b * NHEAD + g] * acc;
        }
    }
}

// ---------------------------------------------------------------------------
// Head mix + f-sum (reads AZh0 once):
//   Zdst[b,g,c] = sum_f Zsrc[b,f,c] * trans[b,f,g]
//   Zsum[b,c]   = sum_f Zsrc[b,f,c]            (c = n*100+i, 20000 per b)
__global__ __launch_bounds__(256) void hmix(
    const float* __restrict__ Zsrc, const float* __restrict__ trans,
    float* __restrict__ Zdst, float* __restrict__ Zsum)
{
    int b = blockIdx.y;
    int c = blockIdx.x * 256 + threadIdx.x;
    __shared__ __align__(8) float tl[NHEAD * NHEAD];
    for (int idx = threadIdx.x; idx < NHEAD * NHEAD; idx += 256) tl[idx] = trans[b * NHEAD * NHEAD + idx];
    __syncthreads();
    if (c >= 20000) return;
    const float* Zb = Zsrc + (size_t)b * NHEAD * 20000 + c;
    float acc[NHEAD];
    #pragma unroll
    for (int g = 0; g < NHEAD; g++) acc[g] = 0.f;
    float s = 0.f;
    for (int f = 0; f < NHEAD; f++) {
        float vf = Zb[(size_t)f * 20000];
        s += vf;
        const float2* row = (const float2*)&tl[f * NHEAD];
        #pragma unroll
        for (int gq = 0; gq < 17; gq++) {
            float2 t2 = row[gq];
            acc[2 * gq]     += vf * t2.x;
            acc[2 * gq + 1] += vf * t2.y;
        }
    }
    Zsum[(size_t)b * 20000 + c] = s;
    float* Zd = Zdst + (size_t)b * NHEAD * 20000 + c;
    #pragma unroll
    for (int g = 0; g < NHEAD; g++) Zd[(size_t)g * 20000] = acc[g];
}

// ---------------------------------------------------------------------------
// out1[b,n,i] = rs1[b,n] * sum_g Zacc[b,g,n,i]
__global__ void fsum_out(const float* __restrict__ Zacc, const float* __restrict__ rs,
                         float* __restrict__ out) {
    int idx = blockIdx.x * 256 + threadIdx.x;
    if (idx >= NBATCH * NNODE * HDIM) return;
    int b = idx / 20000;
    int c = idx % 20000;
    int n = c / 100;
    float s = 0.f;
    #pragma unroll
    for (int g = 0; g < NHEAD; g++) s += Zacc[((size_t)b * NHEAD + g) * 20000 + c];
    out[idx] = s * rs[b * NNODE + n];
}

// ---------------------------------------------------------------------------
extern "C" void kernel_launch(void* const* d_in, const int* in_sizes, int n_in,
                              void* d_out, int out_size, void* d_ws, size_t ws_size,
                              hipStream_t stream) {
    (void)in_sizes; (void)n_in;
    const float* X     = (const float*)d_in[0];
    const float* A     = (const float*)d_in[1];
    const float* start = (const float*)d_in[2];
    const float* endat = (const float*)d_in[3];
    const float* uni   = (const float*)d_in[4];
    const float* trans = (const float*)d_in[5];
    const float* wv    = (const float*)d_in[6];
    float* out = (float*)d_out;
    float* ws  = (float*)d_ws;

    size_t off = 0;
    float* buf1  = ws + off; off += 21760000;   // (b,f,n,o)
    float* buf2  = ws + off; off += 21760000;
    float* dvec0 = ws + off; off += 217600;
    float* Dh0   = ws + off; off += 217600;
    float* dvec1 = ws + off; off += 217600;
    float* Dh1   = ws + off; off += 217600;
    float* rs0   = ws + off; off += 6400;
    float* rs1   = ws + off; off += 6400;
    float* Zsum0 = ws + off; off += 640000;
    if (ws_size < off * sizeof(float)) {
        // sentinel: huge values -> visibly distinct failure mode
        hipMemsetAsync(d_out, 0x7F, (size_t)out_size * sizeof(float), stream);
        return;
    }

    const float* W0  = wv;                 // w_vs[0, 0:34]
    const float* W1  = wv + 350000;        // w_vs[1, 0:34]
    const float* Wi1 = wv + 690000;        // w_vs[1, 34]

    dim3 gBF(NHEAD, NBATCH);

    // t = 0
    dvec0_calc<<<(NBATCH * NHEAD * NNODE + 255) / 256, 256, 0, stream>>>(start, uni, dvec0);
    zh_gemm<<<gBF, 256, 0, stream>>>(X, W0, uni, start, buf1, 0);          // buf1 = Zh0
    a_spmm<<<gBF, 512, 0, stream>>>(A, buf1, dvec0, buf2, Dh0);            // buf2 = AZh0
    dsum_rs<<<(NBATCH * NNODE + 255) / 256, 256, 0, stream>>>(Dh0, endat, rs0);
    dmix<<<NBATCH, 256, 0, stream>>>(Dh0, trans, uni, dvec1);
    hmix<<<dim3(79, NBATCH), 256, 0, stream>>>(buf2, trans, buf1, Zsum0);  // buf1 = Zin1
    zh_gemm<<<dim3(1, NBATCH), 256, 0, stream>>>(Zsum0, Wi1, nullptr, rs0, out, 0); // out[0]

    // t = 1
    zh_gemm<<<gBF, 256, 0, stream>>>(buf1, W1, uni, nullptr, buf2, 1);     // buf2 = Zh1
    a_spmm<<<gBF, 512, 0, stream>>>(A, buf2, dvec1, buf1, Dh1);            // buf1 = AZh1
    dsum_rs<<<(NBATCH * NNODE + 255) / 256, 256, 0, stream>>>(Dh1, endat, rs1);
    fsum_out<<<(NBATCH * NNODE * HDIM + 255) / 256, 256, 0, stream>>>(buf1, rs1, out + 640000);
}

// Round 2
// 663.305 us; speedup vs baseline: 1.3809x; 1.3809x over previous
//
#include <hip/hip_runtime.h>
#include <hip/hip_bf16.h>

#define NHEAD 34
#define HDIM  100
#define NNODE 200
#define NBATCH 32
#define EPSV 1e-20f

// ---------------------------------------------------------------------------
// dvec0[b,f,n] = start[b,n] * uni[b,f]
__global__ void dvec0_calc(const float* __restrict__ start, const float* __restrict__ uni,
                           float* __restrict__ dvec0) {
    int idx = blockIdx.x * 256 + threadIdx.x;
    if (idx >= NBATCH * NHEAD * NNODE) return;
    int b = idx / (NHEAD * NNODE);
    int r = idx % (NHEAD * NNODE);
    int f = r / NNODE;
    int n = r % NNODE;
    dvec0[idx] = start[b * NNODE + n] * uni[b * NHEAD + f];
}

// ---------------------------------------------------------------------------
// Bitmask prepass: A (0/1 fp32, 174 MB) -> 4 u64 per row (256 bits, 7 MB).
// One wave per (b,f,m) row; 16 waves per block.
__global__ __launch_bounds__(1024) void a_bitmask(const float* __restrict__ A,
                                                  unsigned long long* __restrict__ bm) {
    int row = blockIdx.x * 16 + (threadIdx.x >> 6);
    int lane = threadIdx.x & 63;
    if (row >= NBATCH * NHEAD * NNODE) return;
    const float* Ar = A + (size_t)row * NNODE;
    unsigned long long w0 = __ballot(Ar[lane] != 0.0f);
    unsigned long long w1 = __ballot(Ar[64 + lane] != 0.0f);
    unsigned long long w2 = __ballot(Ar[128 + lane] != 0.0f);
    unsigned long long w3 = __ballot(lane < 8 ? (Ar[192 + lane] != 0.0f) : false);
    if (lane == 0) {
        unsigned long long* p = bm + (size_t)row * 4;
        p[0] = w0; p[1] = w1; p[2] = w2; p[3] = w3;
    }
}

// ---------------------------------------------------------------------------
// Generic per-(b,head) GEMM: Dst[b,f,n,o] = u * sum_i S[n,i] * W[f][i,o]
__global__ __launch_bounds__(256) void zh_gemm(
    const float* __restrict__ src, const float* __restrict__ wbase,
    const float* __restrict__ uni, const float* __restrict__ rowscale,
    float* __restrict__ dst, int src_head)
{
    int f = blockIdx.x, b = blockIdx.y;
    int NHg = gridDim.x;
    const float* W = wbase + (size_t)f * 10000;
    const float* S = src + (size_t)(src_head ? (b * NHg + f) : b) * 20000;
    float* Dst = dst + (size_t)(b * NHg + f) * 20000;

    __shared__ __align__(16) float wl[10000];   // W[f]: [i][o], 40KB
    __shared__ __align__(16) float xl[5000];    // 50 input rows, 20KB

    int tid = threadIdx.x;
    for (int idx = tid; idx < 10000; idx += 256) wl[idx] = W[idx];
    float u = uni ? uni[b * NHEAD + f] : 1.0f;

    int q  = tid % 25;   // o-quad: o = 4q..4q+3
    int ty = tid / 25;   // 0..9 active (tid<250)

    for (int c = 0; c < 4; c++) {           // 4 chunks of 50 rows
        __syncthreads();
        int base = c * 5000;
        for (int idx = tid; idx < 5000; idx += 256) {
            int row = idx / 100;
            float sc = rowscale ? rowscale[b * NNODE + c * 50 + row] : 1.0f;
            xl[idx] = S[base + idx] * sc;
        }
        __syncthreads();
        if (ty < 10) {
            float4 acc[5];
            #pragma unroll
            for (int r = 0; r < 5; r++) acc[r] = make_float4(0.f, 0.f, 0.f, 0.f);
            #pragma unroll 2
            for (int i = 0; i < 100; i++) {
                float4 w4 = *(const float4*)&wl[i * 100 + q * 4];
                #pragma unroll
                for (int r = 0; r < 5; r++) {
                    float x = xl[(ty + 10 * r) * 100 + i];
                    acc[r].x += x * w4.x; acc[r].y += x * w4.y;
                    acc[r].z += x * w4.z; acc[r].w += x * w4.w;
                }
            }
            #pragma unroll
            for (int r = 0; r < 5; r++) {
                int n = c * 50 + ty + 10 * r;
                float4 o4 = make_float4(acc[r].x * u, acc[r].y * u, acc[r].z * u, acc[r].w * u);
                *(float4*)&Dst[n * 100 + q * 4] = o4;
            }
        }
    }
}

// ---------------------------------------------------------------------------
// Sparse A-multiply + D-path, one block (1024 thr, 16 waves) per (b,f):
//   Zout[b,f,m,o] = sum_{n: A[m,n]=1} Zin[b,f,n,o]   (Z staged in LDS)
//   Dh[b,f,m]     = sum_{n: A[m,n]=1} dvec[b,f,n]    (lane-parallel bit test)
__global__ __launch_bounds__(1024) void a_spmm2(
    const unsigned long long* __restrict__ bm, const float* __restrict__ Zin,
    const float* __restrict__ dvec, float* __restrict__ Zout, float* __restrict__ Dh)
{
    int f = blockIdx.x, b = blockIdx.y;
    size_t bf = (size_t)b * NHEAD + f;

    __shared__ __align__(16) float zl[20000];            // 80 KB Z slice
    __shared__ float dl[NNODE];
    __shared__ unsigned long long ml[NNODE * 4];         // 6.4 KB masks

    int tid = threadIdx.x;
    const float* Zb = Zin + bf * 20000;
    #pragma unroll
    for (int i = 0; i < 5; i++) {
        int idx = tid + i * 1024;
        if (idx < 5000) *(float4*)&zl[idx * 4] = *(const float4*)&Zb[idx * 4];
    }
    if (tid < NNODE) dl[tid] = dvec[bf * NNODE + tid];
    {
        const unsigned long long* mb = bm + bf * (NNODE * 4);
        if (tid < NNODE * 4) ml[tid] = mb[tid];
    }
    __syncthreads();

    int wave = tid >> 6, lane = tid & 63;
    float* Zob = Zout + bf * 20000;
    int o2 = 2 * lane;
    bool oact = (lane < 50);

    for (int m = wave; m < NNODE; m += 16) {
        unsigned long long m0 = ml[m * 4], m1 = ml[m * 4 + 1];
        unsigned long long m2 = ml[m * 4 + 2], m3 = ml[m * 4 + 3];

        // D path: each lane tests its own bit, then wave-reduce.
        float accd = 0.f;
        if ((m0 >> lane) & 1) accd += dl[lane];
        if ((m1 >> lane) & 1) accd += dl[64 + lane];
        if ((m2 >> lane) & 1) accd += dl[128 + lane];
        if (lane < 8 && ((m3 >> lane) & 1)) accd += dl[192 + lane];
        #pragma unroll
        for (int s = 32; s; s >>= 1) accd += __shfl_xor(accd, s);

        // Z path: serial over set bits (masks are wave-uniform), o-parallel.
        float accx = 0.f, accy = 0.f;
        if (oact) {
            unsigned long long mw[4] = {m0, m1, m2, m3};
            #pragma unroll
            for (int ch = 0; ch < 4; ch++) {
                unsigned long long mask = mw[ch];
                while (mask) {
                    int l = __ffsll((long long)mask) - 1;
                    mask &= mask - 1;
                    int n = ch * 64 + l;
                    const float2 zv = *(const float2*)&zl[n * 100 + o2];
                    accx += zv.x; accy += zv.y;
                }
            }
            *(float2*)&Zob[m * 100 + o2] = make_float2(accx, accy);
        }
        if (lane == 0) Dh[bf * NNODE + m] = accd;
    }
}

// ---------------------------------------------------------------------------
// rs[b,m] = end[b,m] / (end[b,m] * sum_f Dh[b,f,m] + EPS)
__global__ void dsum_rs(const float* __restrict__ Dh, const float* __restrict__ endat,
                        float* __restrict__ rs) {
    int idx = blockIdx.x * 256 + threadIdx.x;
    if (idx >= NBATCH * NNODE) return;
    int b = idx / NNODE, m = idx % NNODE;
    float s = 0.f;
    #pragma unroll
    for (int f = 0; f < NHEAD; f++) s += Dh[((size_t)b * NHEAD + f) * NNODE + m];
    float e = endat[idx];
    rs[idx] = e / (e * s + EPSV);
}

// ---------------------------------------------------------------------------
// dvec1[b,g,n] = uni[b,g] * sum_f Dh0[b,f,n] * trans[b,f,g]
__global__ void dmix(const float* __restrict__ Dh0, const float* __restrict__ trans,
                     const float* __restrict__ uni, float* __restrict__ dvec1) {
    int b = blockIdx.x;
    __shared__ float tl[NHEAD * NHEAD];
    for (int idx = threadIdx.x; idx < NHEAD * NHEAD; idx += 256) tl[idx] = trans[b * NHEAD * NHEAD + idx];
    __syncthreads();
    int n = threadIdx.x;
    if (n < NNODE) {
        float dh[NHEAD];
        #pragma unroll
        for (int f = 0; f < NHEAD; f++) dh[f] = Dh0[((size_t)b * NHEAD + f) * NNODE + n];
        #pragma unroll
        for (int g = 0; g < NHEAD; g++) {
            float acc = 0.f;
            #pragma unroll
            for (int f = 0; f < NHEAD; f++) acc += dh[f] * tl[f * NHEAD + g];
            dvec1[((size_t)b * NHEAD + g) * NNODE + n] = uni[b * NHEAD + g] * acc;
        }
    }
}

// ---------------------------------------------------------------------------
// Head mix + f-sum (reads AZh0 once):
//   Zdst[b,g,c] = sum_f Zsrc[b,f,c] * trans[b,f,g]
//   Zsum[b,c]   = sum_f Zsrc[b,f,c]
__global__ __launch_bounds__(256) void hmix(
    const float* __restrict__ Zsrc, const float* __restrict__ trans,
    float* __restrict__ Zdst, float* __restrict__ Zsum)
{
    int b = blockIdx.y;
    int c = blockIdx.x * 256 + threadIdx.x;
    __shared__ __align__(8) float tl[NHEAD * NHEAD];
    for (int idx = threadIdx.x; idx < NHEAD * NHEAD; idx += 256) tl[idx] = trans[b * NHEAD * NHEAD + idx];
    __syncthreads();
    if (c >= 20000) return;
    const float* Zb = Zsrc + (size_t)b * NHEAD * 20000 + c;
    float acc[NHEAD];
    #pragma unroll
    for (int g = 0; g < NHEAD; g++) acc[g] = 0.f;
    float s = 0.f;
    for (int f = 0; f < NHEAD; f++) {
        float vf = Zb[(size_t)f * 20000];
        s += vf;
        const float2* row = (const float2*)&tl[f * NHEAD];
        #pragma unroll
        for (int gq = 0; gq < 17; gq++) {
            float2 t2 = row[gq];
            acc[2 * gq]     += vf * t2.x;
            acc[2 * gq + 1] += vf * t2.y;
        }
    }
    Zsum[(size_t)b * 20000 + c] = s;
    float* Zd = Zdst + (size_t)b * NHEAD * 20000 + c;
    #pragma unroll
    for (int g = 0; g < NHEAD; g++) Zd[(size_t)g * 20000] = acc[g];
}

// ---------------------------------------------------------------------------
// out1[b,n,i] = rs1[b,n] * sum_g Zacc[b,g,n,i]
__global__ void fsum_out(const float* __restrict__ Zacc, const float* __restrict__ rs,
                         float* __restrict__ out) {
    int idx = blockIdx.x * 256 + threadIdx.x;
    if (idx >= NBATCH * NNODE * HDIM) return;
    int b = idx / 20000;
    int c = idx % 20000;
    int n = c / 100;
    float s = 0.f;
    #pragma unroll
    for (int g = 0; g < NHEAD; g++) s += Zacc[((size_t)b * NHEAD + g) * 20000 + c];
    out[idx] = s * rs[b * NNODE + n];
}

// ---------------------------------------------------------------------------
extern "C" void kernel_launch(void* const* d_in, const int* in_sizes, int n_in,
                              void* d_out, int out_size, void* d_ws, size_t ws_size,
                              hipStream_t stream) {
    (void)in_sizes; (void)n_in;
    const float* X     = (const float*)d_in[0];
    const float* A     = (const float*)d_in[1];
    const float* start = (const float*)d_in[2];
    const float* endat = (const float*)d_in[3];
    const float* uni   = (const float*)d_in[4];
    const float* trans = (const float*)d_in[5];
    const float* wv    = (const float*)d_in[6];
    float* out = (float*)d_out;
    float* ws  = (float*)d_ws;

    size_t off = 0;
    unsigned long long* bm = (unsigned long long*)(ws); off += 1740800; // 217600 rows * 4 u64
    float* buf1  = ws + off; off += 21760000;   // (b,f,n,o)
    float* buf2  = ws + off; off += 21760000;
    float* dvec0 = ws + off; off += 217600;
    float* Dh0   = ws + off; off += 217600;
    float* dvec1 = ws + off; off += 217600;
    float* Dh1   = ws + off; off += 217600;
    float* rs0   = ws + off; off += 6400;
    float* rs1   = ws + off; off += 6400;
    float* Zsum0 = ws + off; off += 640000;
    if (ws_size < off * sizeof(float)) {
        hipMemsetAsync(d_out, 0x7F, (size_t)out_size * sizeof(float), stream);
        return;
    }

    const float* W0  = wv;                 // w_vs[0, 0:34]
    const float* W1  = wv + 350000;        // w_vs[1, 0:34]
    const float* Wi1 = wv + 690000;        // w_vs[1, 34]

    dim3 gBF(NHEAD, NBATCH);

    // prepass: compress A to bitmask (read A exactly once)
    a_bitmask<<<(NBATCH * NHEAD * NNODE + 15) / 16, 1024, 0, stream>>>(A, bm);

    // t = 0
    dvec0_calc<<<(NBATCH * NHEAD * NNODE + 255) / 256, 256, 0, stream>>>(start, uni, dvec0);
    zh_gemm<<<gBF, 256, 0, stream>>>(X, W0, uni, start, buf1, 0);          // buf1 = Zh0
    a_spmm2<<<gBF, 1024, 0, stream>>>(bm, buf1, dvec0, buf2, Dh0);         // buf2 = AZh0
    dsum_rs<<<(NBATCH * NNODE + 255) / 256, 256, 0, stream>>>(Dh0, endat, rs0);
    dmix<<<NBATCH, 256, 0, stream>>>(Dh0, trans, uni, dvec1);
    hmix<<<dim3(79, NBATCH), 256, 0, stream>>>(buf2, trans, buf1, Zsum0);  // buf1 = Zin1
    zh_gemm<<<dim3(1, NBATCH), 256, 0, stream>>>(Zsum0, Wi1, nullptr, rs0, out, 0); // out[0]

    // t = 1
    zh_gemm<<<gBF, 256, 0, stream>>>(buf1, W1, uni, nullptr, buf2, 1);     // buf2 = Zh1
    a_spmm2<<<gBF, 1024, 0, stream>>>(bm, buf2, dvec1, buf1, Dh1);         // buf1 = AZh1
    dsum_rs<<<(NBATCH * NNODE + 255) / 256, 256, 0, stream>>>(Dh1, endat, rs1);
    fsum_out<<<(NBATCH * NNODE * HDIM + 255) / 256, 256, 0, stream>>>(buf1, rs1, out + 640000);
}

// Round 3
// 526.736 us; speedup vs baseline: 1.7389x; 1.2593x over previous
//
#include <hip/hip_runtime.h>
#include <hip/hip_bf16.h>

#define NHEAD 34
#define HDIM  100
#define NNODE 200
#define NBATCH 32
#define EPSV 1e-20f

typedef __attribute__((ext_vector_type(8))) short bf16x8;
typedef __attribute__((ext_vector_type(4))) float f32x4;

__device__ inline unsigned short bf16rne(float x) {
    unsigned u = __builtin_bit_cast(unsigned, x);
    unsigned r = (u + 0x7FFFu + ((u >> 16) & 1u)) >> 16;
    return (unsigned short)r;
}
__device__ inline float bf16tof(unsigned short h) {
    unsigned u = ((unsigned)h) << 16;
    return __builtin_bit_cast(float, u);
}

// split x (fp32) into 3 bf16 parts: x ~= b0 + b1 + b2 (residual ~2^-24|x|)
__device__ inline void split3_8(const float* v, bf16x8& p0, bf16x8& p1, bf16x8& p2) {
    #pragma unroll
    for (int j = 0; j < 8; j++) {
        float x = v[j];
        unsigned short h0 = bf16rne(x); float r1 = x - bf16tof(h0);
        unsigned short h1 = bf16rne(r1); float r2 = r1 - bf16tof(h1);
        unsigned short h2 = bf16rne(r2);
        p0[j] = (short)h0; p1[j] = (short)h1; p2[j] = (short)h2;
    }
}

// ---------------------------------------------------------------------------
// dvec0[b,f,n] = start[b,n] * uni[b,f]
__global__ void dvec0_calc(const float* __restrict__ start, const float* __restrict__ uni,
                           float* __restrict__ dvec0) {
    int idx = blockIdx.x * 256 + threadIdx.x;
    if (idx >= NBATCH * NHEAD * NNODE) return;
    int b = idx / (NHEAD * NNODE);
    int r = idx % (NHEAD * NNODE);
    int f = r / NNODE;
    int n = r % NNODE;
    dvec0[idx] = start[b * NNODE + n] * uni[b * NHEAD + f];
}

// ---------------------------------------------------------------------------
// Bitmask prepass: A (0/1 fp32, 174 MB) -> 4 u64 per row (256 bits, 7 MB).
__global__ __launch_bounds__(1024) void a_bitmask(const float* __restrict__ A,
                                                  unsigned long long* __restrict__ bm) {
    int row = blockIdx.x * 16 + (threadIdx.x >> 6);
    int lane = threadIdx.x & 63;
    if (row >= NBATCH * NHEAD * NNODE) return;
    const float* Ar = A + (size_t)row * NNODE;
    unsigned long long w0 = __ballot(Ar[lane] != 0.0f);
    unsigned long long w1 = __ballot(Ar[64 + lane] != 0.0f);
    unsigned long long w2 = __ballot(Ar[128 + lane] != 0.0f);
    unsigned long long w3 = __ballot(lane < 8 ? (Ar[192 + lane] != 0.0f) : false);
    if (lane == 0) {
        unsigned long long* p = bm + (size_t)row * 4;
        p[0] = w0; p[1] = w1; p[2] = w2; p[3] = w3;
    }
}

// ---------------------------------------------------------------------------
// W split prepass: wfr[fw][frag=nt*4+ks][split][512] bf16 B-fragments.
// fw in 0..67 (t*34+f). B[k][n] = W[k*100+n], k=ks*32+(l>>4)*8+j, n=nt*16+(l&15).
__global__ __launch_bounds__(256) void wsplit(const float* __restrict__ wv,
                                              short* __restrict__ wfr) {
    int fw = blockIdx.x;
    const float* W = wv + (size_t)(fw / 34) * 350000 + (size_t)(fw % 34) * 10000;
    for (int s0 = threadIdx.x; s0 < 28 * 64; s0 += 256) {
        int frag = s0 >> 6;
        int l = s0 & 63;
        int nt = frag >> 2, ks = frag & 3;
        int n = nt * 16 + (l & 15);
        int kb = ks * 32 + ((l >> 4) << 3);
        float v[8];
        #pragma unroll
        for (int j = 0; j < 8; j++) {
            int k = kb + j;
            v[j] = (k < 100 && n < 100) ? W[k * 100 + n] : 0.0f;
        }
        bf16x8 p0, p1, p2;
        split3_8(v, p0, p1, p2);
        size_t base = (((size_t)fw * 28 + frag) * 3) * 512 + l * 8;
        *(bf16x8*)&wfr[base]        = p0;
        *(bf16x8*)&wfr[base + 512]  = p1;
        *(bf16x8*)&wfr[base + 1024] = p2;
    }
}

// ---------------------------------------------------------------------------
// X split prepass (t=0 A operand): xfr[b][frag=mt*4+ks][split][512] bf16
// A[row][k] = X[b,row,k]*start[b,row]; row=mt*16+(l&15), k=ks*32+(l>>4)*8+j.
__global__ __launch_bounds__(256) void asplit(const float* __restrict__ X,
                                              const float* __restrict__ start,
                                              short* __restrict__ xfr) {
    int b = blockIdx.x;
    const float* Xb = X + (size_t)b * 20000;
    const float* st = start + (size_t)b * NNODE;
    for (int s0 = threadIdx.x; s0 < 52 * 64; s0 += 256) {
        int frag = s0 >> 6;
        int l = s0 & 63;
        int mt = frag >> 2, ks = frag & 3;
        int row = mt * 16 + (l & 15);
        int kb = ks * 32 + ((l >> 4) << 3);
        float sc = (row < 200) ? st[row] : 0.0f;
        float v[8];
        #pragma unroll
        for (int j = 0; j < 8; j++) {
            int k = kb + j;
            v[j] = (row < 200 && k < 100) ? Xb[row * 100 + k] * sc : 0.0f;
        }
        bf16x8 p0, p1, p2;
        split3_8(v, p0, p1, p2);
        size_t base = (((size_t)b * 52 + frag) * 3) * 512 + l * 8;
        *(bf16x8*)&xfr[base]        = p0;
        *(bf16x8*)&xfr[base + 512]  = p1;
        *(bf16x8*)&xfr[base + 1024] = p2;
    }
}

// ---------------------------------------------------------------------------
// MFMA GEMM: Dst[b,f,n,o] = u * sum_i S[n,i]*W[f][i,o], fp32 via 3-way bf16
// split (6 products). Block = (b,f), 256 thr = 4 waves; wave owns 2 N-tiles
// (B-frags cached in VGPRs). A-frags: t=0 from global xfr; t=1 converted
// in-kernel into LDS (chunks of 5 M-tiles, 60KB).
template <bool AFROMG>
__global__ __launch_bounds__(256, 2) void mfma_zh(
    const short* __restrict__ afr_g,   // [b][52][3][512] (AFROMG)
    const float* __restrict__ src,     // [b][f][200][100] (!AFROMG)
    const short* __restrict__ wfr_t,   // [f][28][3][512]
    const float* __restrict__ uni,
    float* __restrict__ dst)
{
    int f = blockIdx.x, b = blockIdx.y;
    int tid = threadIdx.x;
    int lane = tid & 63, w = tid >> 6;
    int nt0 = 2 * w, nt1 = 2 * w + 1;
    bool has1 = (nt1 <= 6);

    __shared__ short afr[5 * 4 * 3 * 512];   // 60 KB

    const float* S = src + (size_t)(b * NHEAD + f) * 20000;
    const short* AG = afr_g + (size_t)b * (52 * 3 * 512);
    float* Dst = dst + (size_t)(b * NHEAD + f) * 20000;
    float u = uni[b * NHEAD + f];

    // cache B fragments for the wave's N-tiles
    bf16x8 Bc0[4][3], Bc1[4][3];
    bf16x8 zv = 0;
    #pragma unroll
    for (int ks = 0; ks < 4; ks++)
        #pragma unroll
        for (int s = 0; s < 3; s++) {
            Bc0[ks][s] = *(const bf16x8*)&wfr_t[(((size_t)f * 28 + nt0 * 4 + ks) * 3 + s) * 512 + lane * 8];
            Bc1[ks][s] = has1 ? *(const bf16x8*)&wfr_t[(((size_t)f * 28 + nt1 * 4 + ks) * 3 + s) * 512 + lane * 8] : zv;
        }

    for (int c = 0; c < 13; c += 5) {
        int nmt = (13 - c < 5) ? (13 - c) : 5;
        if constexpr (!AFROMG) {
            __syncthreads();
            int nslots = nmt * 4 * 64;
            for (int s0 = tid; s0 < nslots; s0 += 256) {
                int mtl = s0 >> 8;
                int ks = (s0 >> 6) & 3;
                int l = s0 & 63;
                int row = (c + mtl) * 16 + (l & 15);
                int kb = ks * 32 + ((l >> 4) << 3);
                float v[8];
                #pragma unroll
                for (int j = 0; j < 8; j++) {
                    int k = kb + j;
                    v[j] = (row < 200 && k < 100) ? S[row * 100 + k] : 0.0f;
                }
                bf16x8 p0, p1, p2;
                split3_8(v, p0, p1, p2);
                int base = ((mtl * 4 + ks) * 3) * 512 + l * 8;
                *(bf16x8*)&afr[base]        = p0;
                *(bf16x8*)&afr[base + 512]  = p1;
                *(bf16x8*)&afr[base + 1024] = p2;
            }
            __syncthreads();
        }
        for (int mtl = 0; mtl < nmt; mtl++) {
            int mt = c + mtl;
            bf16x8 Af[4][3];
            #pragma unroll
            for (int ks = 0; ks < 4; ks++)
                #pragma unroll
                for (int s = 0; s < 3; s++) {
                    if constexpr (AFROMG)
                        Af[ks][s] = *(const bf16x8*)&AG[((size_t)(mt * 4 + ks) * 3 + s) * 512 + lane * 8];
                    else
                        Af[ks][s] = *(const bf16x8*)&afr[((mtl * 4 + ks) * 3 + s) * 512 + lane * 8];
                }
            f32x4 acc0 = {0.f, 0.f, 0.f, 0.f};
            f32x4 acc1 = {0.f, 0.f, 0.f, 0.f};
            #pragma unroll
            for (int ks = 0; ks < 4; ks++) {
                acc0 = __builtin_amdgcn_mfma_f32_16x16x32_bf16(Af[ks][0], Bc0[ks][0], acc0, 0, 0, 0);
                acc1 = __builtin_amdgcn_mfma_f32_16x16x32_bf16(Af[ks][0], Bc1[ks][0], acc1, 0, 0, 0);
                acc0 = __builtin_amdgcn_mfma_f32_16x16x32_bf16(Af[ks][0], Bc0[ks][1], acc0, 0, 0, 0);
                acc1 = __builtin_amdgcn_mfma_f32_16x16x32_bf16(Af[ks][0], Bc1[ks][1], acc1, 0, 0, 0);
                acc0 = __builtin_amdgcn_mfma_f32_16x16x32_bf16(Af[ks][1], Bc0[ks][0], acc0, 0, 0, 0);
                acc1 = __builtin_amdgcn_mfma_f32_16x16x32_bf16(Af[ks][1], Bc1[ks][0], acc1, 0, 0, 0);
                acc0 = __builtin_amdgcn_mfma_f32_16x16x32_bf16(Af[ks][0], Bc0[ks][2], acc0, 0, 0, 0);
                acc1 = __builtin_amdgcn_mfma_f32_16x16x32_bf16(Af[ks][0], Bc1[ks][2], acc1, 0, 0, 0);
                acc0 = __builtin_amdgcn_mfma_f32_16x16x32_bf16(Af[ks][1], Bc0[ks][1], acc0, 0, 0, 0);
                acc1 = __builtin_amdgcn_mfma_f32_16x16x32_bf16(Af[ks][1], Bc1[ks][1], acc1, 0, 0, 0);
                acc0 = __builtin_amdgcn_mfma_f32_16x16x32_bf16(Af[ks][2], Bc0[ks][0], acc0, 0, 0, 0);
                acc1 = __builtin_amdgcn_mfma_f32_16x16x32_bf16(Af[ks][2], Bc1[ks][0], acc1, 0, 0, 0);
            }
            // D layout: col = lane&15, row = (lane>>4)*4 + reg   [m89-verified]
            int cl = lane & 15;
            int rbase = mt * 16 + (lane >> 4) * 4;
            #pragma unroll
            for (int reg = 0; reg < 4; reg++) {
                int R = rbase + reg;
                if (R < 200) {
                    int C0 = nt0 * 16 + cl;
                    if (C0 < 100) Dst[R * 100 + C0] = acc0[reg] * u;
                    if (has1) {
                        int C1 = nt1 * 16 + cl;
                        if (C1 < 100) Dst[R * 100 + C1] = acc1[reg] * u;
                    }
                }
            }
        }
    }
}

// ---------------------------------------------------------------------------
// fp32 fallback GEMM (kept for the small out0 GEMM): Dst[b,n,o] =
//   sum_i (rowscale*S)[n,i] * W[i,o]
__global__ __launch_bounds__(256) void zh_gemm(
    const float* __restrict__ src, const float* __restrict__ wbase,
    const float* __restrict__ uni, const float* __restrict__ rowscale,
    float* __restrict__ dst, int src_head)
{
    int f = blockIdx.x, b = blockIdx.y;
    int NHg = gridDim.x;
    const float* W = wbase + (size_t)f * 10000;
    const float* S = src + (size_t)(src_head ? (b * NHg + f) : b) * 20000;
    float* Dst = dst + (size_t)(b * NHg + f) * 20000;

    __shared__ __align__(16) float wl[10000];
    __shared__ __align__(16) float xl[5000];

    int tid = threadIdx.x;
    for (int idx = tid; idx < 10000; idx += 256) wl[idx] = W[idx];
    float u = uni ? uni[b * NHEAD + f] : 1.0f;

    int q = tid % 25;
    int ty = tid / 25;

    for (int c = 0; c < 4; c++) {
        __syncthreads();
        int base = c * 5000;
        for (int idx = tid; idx < 5000; idx += 256) {
            int row = idx / 100;
            float sc = rowscale ? rowscale[b * NNODE + c * 50 + row] : 1.0f;
            xl[idx] = S[base + idx] * sc;
        }
        __syncthreads();
        if (ty < 10) {
            float4 acc[5];
            #pragma unroll
            for (int r = 0; r < 5; r++) acc[r] = make_float4(0.f, 0.f, 0.f, 0.f);
            #pragma unroll 2
            for (int i = 0; i < 100; i++) {
                float4 w4 = *(const float4*)&wl[i * 100 + q * 4];
                #pragma unroll
                for (int r = 0; r < 5; r++) {
                    float x = xl[(ty + 10 * r) * 100 + i];
                    acc[r].x += x * w4.x; acc[r].y += x * w4.y;
                    acc[r].z += x * w4.z; acc[r].w += x * w4.w;
                }
            }
            #pragma unroll
            for (int r = 0; r < 5; r++) {
                int n = c * 50 + ty + 10 * r;
                float4 o4 = make_float4(acc[r].x * u, acc[r].y * u, acc[r].z * u, acc[r].w * u);
                *(float4*)&Dst[n * 100 + q * 4] = o4;
            }
        }
    }
}

// ---------------------------------------------------------------------------
// Sparse A-multiply + D-path (bitmask, LDS-staged Z).
__global__ __launch_bounds__(1024) void a_spmm2(
    const unsigned long long* __restrict__ bm, const float* __restrict__ Zin,
    const float* __restrict__ dvec, float* __restrict__ Zout, float* __restrict__ Dh)
{
    int f = blockIdx.x, b = blockIdx.y;
    size_t bf = (size_t)b * NHEAD + f;

    __shared__ __align__(16) float zl[20000];
    __shared__ float dl[NNODE];
    __shared__ unsigned long long ml[NNODE * 4];

    int tid = threadIdx.x;
    const float* Zb = Zin + bf * 20000;
    #pragma unroll
    for (int i = 0; i < 5; i++) {
        int idx = tid + i * 1024;
        if (idx < 5000) *(float4*)&zl[idx * 4] = *(const float4*)&Zb[idx * 4];
    }
    if (tid < NNODE) dl[tid] = dvec[bf * NNODE + tid];
    {
        const unsigned long long* mb = bm + bf * (NNODE * 4);
        if (tid < NNODE * 4) ml[tid] = mb[tid];
    }
    __syncthreads();

    int wave = tid >> 6, lane = tid & 63;
    float* Zob = Zout + bf * 20000;
    int o2 = 2 * lane;
    bool oact = (lane < 50);

    for (int m = wave; m < NNODE; m += 16) {
        unsigned long long m0 = ml[m * 4], m1 = ml[m * 4 + 1];
        unsigned long long m2 = ml[m * 4 + 2], m3 = ml[m * 4 + 3];

        float accd = 0.f;
        if ((m0 >> lane) & 1) accd += dl[lane];
        if ((m1 >> lane) & 1) accd += dl[64 + lane];
        if ((m2 >> lane) & 1) accd += dl[128 + lane];
        if (lane < 8 && ((m3 >> lane) & 1)) accd += dl[192 + lane];
        #pragma unroll
        for (int s = 32; s; s >>= 1) accd += __shfl_xor(accd, s);

        float accx = 0.f, accy = 0.f;
        if (oact) {
            unsigned long long mw[4] = {m0, m1, m2, m3};
            #pragma unroll
            for (int ch = 0; ch < 4; ch++) {
                unsigned long long mask = mw[ch];
                while (mask) {
                    int l = __ffsll((long long)mask) - 1;
                    mask &= mask - 1;
                    int n = ch * 64 + l;
                    const float2 zv = *(const float2*)&zl[n * 100 + o2];
                    accx += zv.x; accy += zv.y;
                }
            }
            *(float2*)&Zob[m * 100 + o2] = make_float2(accx, accy);
        }
        if (lane == 0) Dh[bf * NNODE + m] = accd;
    }
}

// ---------------------------------------------------------------------------
__global__ void dsum_rs(const float* __restrict__ Dh, const float* __restrict__ endat,
                        float* __restrict__ rs) {
    int idx = blockIdx.x * 256 + threadIdx.x;
    if (idx >= NBATCH * NNODE) return;
    int b = idx / NNODE, m = idx % NNODE;
    float s = 0.f;
    #pragma unroll
    for (int f = 0; f < NHEAD; f++) s += Dh[((size_t)b * NHEAD + f) * NNODE + m];
    float e = endat[idx];
    rs[idx] = e / (e * s + EPSV);
}

// ---------------------------------------------------------------------------
__global__ void dmix(const float* __restrict__ Dh0, const float* __restrict__ trans,
                     const float* __restrict__ uni, float* __restrict__ dvec1) {
    int b = blockIdx.x;
    __shared__ float tl[NHEAD * NHEAD];
    for (int idx = threadIdx.x; idx < NHEAD * NHEAD; idx += 256) tl[idx] = trans[b * NHEAD * NHEAD + idx];
    __syncthreads();
    int n = threadIdx.x;
    if (n < NNODE) {
        float dh[NHEAD];
        #pragma unroll
        for (int f = 0; f < NHEAD; f++) dh[f] = Dh0[((size_t)b * NHEAD + f) * NNODE + n];
        #pragma unroll
        for (int g = 0; g < NHEAD; g++) {
            float acc = 0.f;
            #pragma unroll
            for (int f = 0; f < NHEAD; f++) acc += dh[f] * tl[f * NHEAD + g];
            dvec1[((size_t)b * NHEAD + g) * NNODE + n] = uni[b * NHEAD + g] * acc;
        }
    }
}

// ---------------------------------------------------------------------------
__global__ __launch_bounds__(256) void hmix(
    const float* __restrict__ Zsrc, const float* __restrict__ trans,
    float* __restrict__ Zdst, float* __restrict__ Zsum)
{
    int b = blockIdx.y;
    int c = blockIdx.x * 256 + threadIdx.x;
    __shared__ __align__(8) float tl[NHEAD * NHEAD];
    for (int idx = threadIdx.x; idx < NHEAD * NHEAD; idx += 256) tl[idx] = trans[b * NHEAD * NHEAD + idx];
    __syncthreads();
    if (c >= 20000) return;
    const float* Zb = Zsrc + (size_t)b * NHEAD * 20000 + c;
    float acc[NHEAD];
    #pragma unroll
    for (int g = 0; g < NHEAD; g++) acc[g] = 0.f;
    float s = 0.f;
    for (int f = 0; f < NHEAD; f++) {
        float vf = Zb[(size_t)f * 20000];
        s += vf;
        const float2* row = (const float2*)&tl[f * NHEAD];
        #pragma unroll
        for (int gq = 0; gq < 17; gq++) {
            float2 t2 = row[gq];
            acc[2 * gq]     += vf * t2.x;
            acc[2 * gq + 1] += vf * t2.y;
        }
    }
    Zsum[(size_t)b * 20000 + c] = s;
    float* Zd = Zdst + (size_t)b * NHEAD * 20000 + c;
    #pragma unroll
    for (int g = 0; g < NHEAD; g++) Zd[(size_t)g * 20000] = acc[g];
}

// ---------------------------------------------------------------------------
__global__ void fsum_out(const float* __restrict__ Zacc, const float* __restrict__ rs,
                         float* __restrict__ out) {
    int idx = blockIdx.x * 256 + threadIdx.x;
    if (idx >= NBATCH * NNODE * HDIM) return;
    int b = idx / 20000;
    int c = idx % 20000;
    int n = c / 100;
    float s = 0.f;
    #pragma unroll
    for (int g = 0; g < NHEAD; g++) s += Zacc[((size_t)b * NHEAD + g) * 20000 + c];
    out[idx] = s * rs[b * NNODE + n];
}

// ---------------------------------------------------------------------------
extern "C" void kernel_launch(void* const* d_in, const int* in_sizes, int n_in,
                              void* d_out, int out_size, void* d_ws, size_t ws_size,
                              hipStream_t stream) {
    (void)in_sizes; (void)n_in;
    const float* X     = (const float*)d_in[0];
    const float* A     = (const float*)d_in[1];
    const float* start = (const float*)d_in[2];
    const float* endat = (const float*)d_in[3];
    const float* uni   = (const float*)d_in[4];
    const float* trans = (const float*)d_in[5];
    const float* wv    = (const float*)d_in[6];
    float* out = (float*)d_out;
    float* ws  = (float*)d_ws;

    size_t off = 0;
    unsigned long long* bm = (unsigned long long*)(ws); off += 1740800;
    float* buf1  = ws + off; off += 21760000;
    float* buf2  = ws + off; off += 21760000;
    float* dvec0 = ws + off; off += 217600;
    float* Dh0   = ws + off; off += 217600;
    float* dvec1 = ws + off; off += 217600;
    float* Dh1   = ws + off; off += 217600;
    float* rs0   = ws + off; off += 6400;
    float* rs1   = ws + off; off += 6400;
    float* Zsum0 = ws + off; off += 640000;
    short* wfr   = (short*)(ws + off); off += 1462272;  // 68*28*3*512 shorts
    short* xfr   = (short*)(ws + off); off += 1277952;  // 32*52*3*512 shorts
    if (ws_size < off * sizeof(float)) {
        hipMemsetAsync(d_out, 0x7F, (size_t)out_size * sizeof(float), stream);
        return;
    }

    const float* Wi1 = wv + 690000;        // w_vs[1, 34]
    const short* wfr0 = wfr;
    const short* wfr1 = wfr + (size_t)34 * 28 * 3 * 512;

    dim3 gBF(NHEAD, NBATCH);

    // prepasses
    a_bitmask<<<(NBATCH * NHEAD * NNODE + 15) / 16, 1024, 0, stream>>>(A, bm);
    wsplit<<<68, 256, 0, stream>>>(wv, wfr);
    asplit<<<32, 256, 0, stream>>>(X, start, xfr);
    dvec0_calc<<<(NBATCH * NHEAD * NNODE + 255) / 256, 256, 0, stream>>>(start, uni, dvec0);

    // t = 0
    mfma_zh<true><<<gBF, 256, 0, stream>>>(xfr, nullptr, wfr0, uni, buf1);   // buf1 = Zh0
    a_spmm2<<<gBF, 1024, 0, stream>>>(bm, buf1, dvec0, buf2, Dh0);           // buf2 = AZh0
    dsum_rs<<<(NBATCH * NNODE + 255) / 256, 256, 0, stream>>>(Dh0, endat, rs0);
    dmix<<<NBATCH, 256, 0, stream>>>(Dh0, trans, uni, dvec1);
    hmix<<<dim3(79, NBATCH), 256, 0, stream>>>(buf2, trans, buf1, Zsum0);    // buf1 = Zin1
    zh_gemm<<<dim3(1, NBATCH), 256, 0, stream>>>(Zsum0, Wi1, nullptr, rs0, out, 0); // out[0]

    // t = 1
    mfma_zh<false><<<gBF, 256, 0, stream>>>(nullptr, buf1, wfr1, uni, buf2); // buf2 = Zh1
    a_spmm2<<<gBF, 1024, 0, stream>>>(bm, buf2, dvec1, buf1, Dh1);           // buf1 = AZh1
    dsum_rs<<<(NBATCH * NNODE + 255) / 256, 256, 0, stream>>>(Dh1, endat, rs1);
    fsum_out<<<(NBATCH * NNODE * HDIM + 255) / 256, 256, 0, stream>>>(buf1, rs1, out + 640000);
}

// Round 4
// 434.986 us; speedup vs baseline: 2.1057x; 1.2109x over previous
//
#include <hip/hip_runtime.h>
#include <hip/hip_bf16.h>

#define NHEAD 34
#define HDIM  100
#define NNODE 200
#define NBATCH 32
#define EPSV 1e-20f

typedef __attribute__((ext_vector_type(8))) short bf16x8;
typedef __attribute__((ext_vector_type(4))) float f32x4;
typedef __attribute__((ext_vector_type(16))) float f32x16;
typedef __attribute__((ext_vector_type(4))) unsigned int ux4;

__device__ inline unsigned short bf16rne(float x) {
    unsigned u = __builtin_bit_cast(unsigned, x);
    unsigned r = (u + 0x7FFFu + ((u >> 16) & 1u)) >> 16;
    return (unsigned short)r;
}
__device__ inline float bf16tof(unsigned short h) {
    unsigned u = ((unsigned)h) << 16;
    return __builtin_bit_cast(float, u);
}

// split x (fp32) into 3 bf16 parts: x ~= b0 + b1 + b2 (residual ~2^-24|x|)
__device__ inline void split3_8(const float* v, bf16x8& p0, bf16x8& p1, bf16x8& p2) {
    #pragma unroll
    for (int j = 0; j < 8; j++) {
        float x = v[j];
        unsigned short h0 = bf16rne(x); float r1 = x - bf16tof(h0);
        unsigned short h1 = bf16rne(r1); float r2 = r1 - bf16tof(h1);
        unsigned short h2 = bf16rne(r2);
        p0[j] = (short)h0; p1[j] = (short)h1; p2[j] = (short)h2;
    }
}

// truncation-based 3-split + pack for MFMA fragment regs (lo=elem 2r, hi=2r+1)
__device__ inline void zsplit_pack(const float* zv, bf16x8& s0, bf16x8& s1, bf16x8& s2) {
    unsigned u0[8], u1[8], u2[8];
    #pragma unroll
    for (int j = 0; j < 8; j++) {
        float x = zv[j];
        unsigned ux = __builtin_bit_cast(unsigned, x);
        unsigned h0 = ux & 0xFFFF0000u;
        float r1 = x - __builtin_bit_cast(float, h0);
        unsigned u1x = __builtin_bit_cast(unsigned, r1);
        unsigned h1 = u1x & 0xFFFF0000u;
        float r2 = r1 - __builtin_bit_cast(float, h1);
        u0[j] = ux; u1[j] = u1x; u2[j] = __builtin_bit_cast(unsigned, r2);
    }
    ux4 p0, p1, p2;
    #pragma unroll
    for (int r = 0; r < 4; r++) {
        p0[r] = (u0[2 * r] >> 16) | (u0[2 * r + 1] & 0xFFFF0000u);
        p1[r] = (u1[2 * r] >> 16) | (u1[2 * r + 1] & 0xFFFF0000u);
        p2[r] = (u2[2 * r] >> 16) | (u2[2 * r + 1] & 0xFFFF0000u);
    }
    s0 = __builtin_bit_cast(bf16x8, p0);
    s1 = __builtin_bit_cast(bf16x8, p1);
    s2 = __builtin_bit_cast(bf16x8, p2);
}

// 8 mask bits -> bf16x8 of 0.0/1.0
__device__ inline bf16x8 afrag_bits(unsigned byte) {
    ux4 p;
    #pragma unroll
    for (int r = 0; r < 4; r++) {
        p[r] = ((byte >> (2 * r)) & 1u) * 0x3F80u + ((byte >> (2 * r + 1)) & 1u) * 0x3F800000u;
    }
    return __builtin_bit_cast(bf16x8, p);
}

// ---------------------------------------------------------------------------
// dvec0[b,f,n] = start[b,n] * uni[b,f]
__global__ void dvec0_calc(const float* __restrict__ start, const float* __restrict__ uni,
                           float* __restrict__ dvec0) {
    int idx = blockIdx.x * 256 + threadIdx.x;
    if (idx >= NBATCH * NHEAD * NNODE) return;
    int b = idx / (NHEAD * NNODE);
    int r = idx % (NHEAD * NNODE);
    int f = r / NNODE;
    int n = r % NNODE;
    dvec0[idx] = start[b * NNODE + n] * uni[b * NHEAD + f];
}

// ---------------------------------------------------------------------------
// Bitmask prepass: A (0/1 fp32, 174 MB) -> 4 u64 per row (256 bits, 7 MB).
__global__ __launch_bounds__(1024) void a_bitmask(const float* __restrict__ A,
                                                  unsigned long long* __restrict__ bm) {
    int row = blockIdx.x * 16 + (threadIdx.x >> 6);
    int lane = threadIdx.x & 63;
    if (row >= NBATCH * NHEAD * NNODE) return;
    const float* Ar = A + (size_t)row * NNODE;
    unsigned long long w0 = __ballot(Ar[lane] != 0.0f);
    unsigned long long w1 = __ballot(Ar[64 + lane] != 0.0f);
    unsigned long long w2 = __ballot(Ar[128 + lane] != 0.0f);
    unsigned long long w3 = __ballot(lane < 8 ? (Ar[192 + lane] != 0.0f) : false);
    if (lane == 0) {
        unsigned long long* p = bm + (size_t)row * 4;
        p[0] = w0; p[1] = w1; p[2] = w2; p[3] = w3;
    }
}

// ---------------------------------------------------------------------------
// W split prepass: wfr[fw][frag=nt*4+ks][split][512] bf16 B-fragments.
__global__ __launch_bounds__(256) void wsplit(const float* __restrict__ wv,
                                              short* __restrict__ wfr) {
    int fw = blockIdx.x;
    const float* W = wv + (size_t)(fw / 34) * 350000 + (size_t)(fw % 34) * 10000;
    for (int s0 = threadIdx.x; s0 < 28 * 64; s0 += 256) {
        int frag = s0 >> 6;
        int l = s0 & 63;
        int nt = frag >> 2, ks = frag & 3;
        int n = nt * 16 + (l & 15);
        int kb = ks * 32 + ((l >> 4) << 3);
        float v[8];
        #pragma unroll
        for (int j = 0; j < 8; j++) {
            int k = kb + j;
            v[j] = (k < 100 && n < 100) ? W[k * 100 + n] : 0.0f;
        }
        bf16x8 p0, p1, p2;
        split3_8(v, p0, p1, p2);
        size_t base = (((size_t)fw * 28 + frag) * 3) * 512 + l * 8;
        *(bf16x8*)&wfr[base]        = p0;
        *(bf16x8*)&wfr[base + 512]  = p1;
        *(bf16x8*)&wfr[base + 1024] = p2;
    }
}

// ---------------------------------------------------------------------------
// X split prepass (t=0 A operand): xfr[b][frag=mt*4+ks][split][512] bf16
__global__ __launch_bounds__(256) void asplit(const float* __restrict__ X,
                                              const float* __restrict__ start,
                                              short* __restrict__ xfr) {
    int b = blockIdx.x;
    const float* Xb = X + (size_t)b * 20000;
    const float* st = start + (size_t)b * NNODE;
    for (int s0 = threadIdx.x; s0 < 52 * 64; s0 += 256) {
        int frag = s0 >> 6;
        int l = s0 & 63;
        int mt = frag >> 2, ks = frag & 3;
        int row = mt * 16 + (l & 15);
        int kb = ks * 32 + ((l >> 4) << 3);
        float sc = (row < 200) ? st[row] : 0.0f;
        float v[8];
        #pragma unroll
        for (int j = 0; j < 8; j++) {
            int k = kb + j;
            v[j] = (row < 200 && k < 100) ? Xb[row * 100 + k] * sc : 0.0f;
        }
        bf16x8 p0, p1, p2;
        split3_8(v, p0, p1, p2);
        size_t base = (((size_t)b * 52 + frag) * 3) * 512 + l * 8;
        *(bf16x8*)&xfr[base]        = p0;
        *(bf16x8*)&xfr[base + 512]  = p1;
        *(bf16x8*)&xfr[base + 1024] = p2;
    }
}

// ---------------------------------------------------------------------------
// MFMA GEMM: Dst[b,f,n,o] = u * sum_i S[n,i]*W[f][i,o], fp32 via 3-way bf16
// split (6 products). 16x16x32 shape.
template <bool AFROMG>
__global__ __launch_bounds__(256, 2) void mfma_zh(
    const short* __restrict__ afr_g,   // [b][52][3][512] (AFROMG)
    const float* __restrict__ src,     // [b][f][200][100] (!AFROMG)
    const short* __restrict__ wfr_t,   // [f][28][3][512]
    const float* __restrict__ uni,
    float* __restrict__ dst)
{
    int f = blockIdx.x, b = blockIdx.y;
    int tid = threadIdx.x;
    int lane = tid & 63, w = tid >> 6;
    int nt0 = 2 * w, nt1 = 2 * w + 1;
    bool has1 = (nt1 <= 6);

    __shared__ short afr[5 * 4 * 3 * 512];   // 60 KB

    const float* S = src + (size_t)(b * NHEAD + f) * 20000;
    const short* AG = afr_g + (size_t)b * (52 * 3 * 512);
    float* Dst = dst + (size_t)(b * NHEAD + f) * 20000;
    float u = uni[b * NHEAD + f];

    bf16x8 Bc0[4][3], Bc1[4][3];
    bf16x8 zv = 0;
    #pragma unroll
    for (int ks = 0; ks < 4; ks++)
        #pragma unroll
        for (int s = 0; s < 3; s++) {
            Bc0[ks][s] = *(const bf16x8*)&wfr_t[(((size_t)f * 28 + nt0 * 4 + ks) * 3 + s) * 512 + lane * 8];
            Bc1[ks][s] = has1 ? *(const bf16x8*)&wfr_t[(((size_t)f * 28 + nt1 * 4 + ks) * 3 + s) * 512 + lane * 8] : zv;
        }

    for (int c = 0; c < 13; c += 5) {
        int nmt = (13 - c < 5) ? (13 - c) : 5;
        if constexpr (!AFROMG) {
            __syncthreads();
            int nslots = nmt * 4 * 64;
            for (int s0 = tid; s0 < nslots; s0 += 256) {
                int mtl = s0 >> 8;
                int ks = (s0 >> 6) & 3;
                int l = s0 & 63;
                int row = (c + mtl) * 16 + (l & 15);
                int kb = ks * 32 + ((l >> 4) << 3);
                float v[8];
                #pragma unroll
                for (int j = 0; j < 8; j++) {
                    int k = kb + j;
                    v[j] = (row < 200 && k < 100) ? S[row * 100 + k] : 0.0f;
                }
                bf16x8 p0, p1, p2;
                split3_8(v, p0, p1, p2);
                int base = ((mtl * 4 + ks) * 3) * 512 + l * 8;
                *(bf16x8*)&afr[base]        = p0;
                *(bf16x8*)&afr[base + 512]  = p1;
                *(bf16x8*)&afr[base + 1024] = p2;
            }
            __syncthreads();
        }
        for (int mtl = 0; mtl < nmt; mtl++) {
            int mt = c + mtl;
            bf16x8 Af[4][3];
            #pragma unroll
            for (int ks = 0; ks < 4; ks++)
                #pragma unroll
                for (int s = 0; s < 3; s++) {
                    if constexpr (AFROMG)
                        Af[ks][s] = *(const bf16x8*)&AG[((size_t)(mt * 4 + ks) * 3 + s) * 512 + lane * 8];
                    else
                        Af[ks][s] = *(const bf16x8*)&afr[((mtl * 4 + ks) * 3 + s) * 512 + lane * 8];
                }
            f32x4 acc0 = {0.f, 0.f, 0.f, 0.f};
            f32x4 acc1 = {0.f, 0.f, 0.f, 0.f};
            #pragma unroll
            for (int ks = 0; ks < 4; ks++) {
                acc0 = __builtin_amdgcn_mfma_f32_16x16x32_bf16(Af[ks][0], Bc0[ks][0], acc0, 0, 0, 0);
                acc1 = __builtin_amdgcn_mfma_f32_16x16x32_bf16(Af[ks][0], Bc1[ks][0], acc1, 0, 0, 0);
                acc0 = __builtin_amdgcn_mfma_f32_16x16x32_bf16(Af[ks][0], Bc0[ks][1], acc0, 0, 0, 0);
                acc1 = __builtin_amdgcn_mfma_f32_16x16x32_bf16(Af[ks][0], Bc1[ks][1], acc1, 0, 0, 0);
                acc0 = __builtin_amdgcn_mfma_f32_16x16x32_bf16(Af[ks][1], Bc0[ks][0], acc0, 0, 0, 0);
                acc1 = __builtin_amdgcn_mfma_f32_16x16x32_bf16(Af[ks][1], Bc1[ks][0], acc1, 0, 0, 0);
                acc0 = __builtin_amdgcn_mfma_f32_16x16x32_bf16(Af[ks][0], Bc0[ks][2], acc0, 0, 0, 0);
                acc1 = __builtin_amdgcn_mfma_f32_16x16x32_bf16(Af[ks][0], Bc1[ks][2], acc1, 0, 0, 0);
                acc0 = __builtin_amdgcn_mfma_f32_16x16x32_bf16(Af[ks][1], Bc0[ks][1], acc0, 0, 0, 0);
                acc1 = __builtin_amdgcn_mfma_f32_16x16x32_bf16(Af[ks][1], Bc1[ks][1], acc1, 0, 0, 0);
                acc0 = __builtin_amdgcn_mfma_f32_16x16x32_bf16(Af[ks][2], Bc0[ks][0], acc0, 0, 0, 0);
                acc1 = __builtin_amdgcn_mfma_f32_16x16x32_bf16(Af[ks][2], Bc1[ks][0], acc1, 0, 0, 0);
            }
            int cl = lane & 15;
            int rbase = mt * 16 + (lane >> 4) * 4;
            #pragma unroll
            for (int reg = 0; reg < 4; reg++) {
                int R = rbase + reg;
                if (R < 200) {
                    int C0 = nt0 * 16 + cl;
                    if (C0 < 100) Dst[R * 100 + C0] = acc0[reg] * u;
                    if (has1) {
                        int C1 = nt1 * 16 + cl;
                        if (C1 < 100) Dst[R * 100 + C1] = acc1[reg] * u;
                    }
                }
            }
        }
    }
}

// ---------------------------------------------------------------------------
// Dense MFMA A-multiply (replaces bit-gather spmm):
//   Zout[b,f,m,o] = sum_n A[b,f,m,n] * Zin[b,f,n,o]
//   Dh[b,f,m]     = sum_n A[b,f,m,n] * dvec[b,f,n]   (dvec rides as col 100)
// A-frags built in registers from the bitmask; Z 3-way truncation split.
// 32x32x16 MFMA: m-tiles 7 (224), n(col)-tiles 4 (128), k-steps 13 (208).
// 8 waves = 2 m-groups (4/3 tiles) x 4 col-tiles.
__global__ __launch_bounds__(512) void a_mfma(
    const unsigned* __restrict__ bm32, const float* __restrict__ Zin,
    const float* __restrict__ dvec, float* __restrict__ Zout, float* __restrict__ Dh)
{
    int f = blockIdx.x, b = blockIdx.y;
    size_t bf = (size_t)b * NHEAD + f;

    __shared__ unsigned mkl[8 * 208];                 // masks transposed [w][m]
    __shared__ __align__(16) float zl[2][16 * 128];   // k-slab, dbuf, 16 KB

    int tid = threadIdx.x;
    const float* Zb = Zin + bf * 20000;
    const float* dv = dvec + bf * 200;
    const unsigned* bmw = bm32 + bf * 1600;           // [m][w] u32

    for (int idx = tid; idx < 1600; idx += 512) {
        int m = idx >> 3, wq = idx & 7;
        mkl[wq * 208 + m] = bmw[idx];
    }
    if (tid < 64) mkl[(tid >> 3) * 208 + 200 + (tid & 7)] = 0u;

    {   // stage ks=0
        int r = tid >> 5, cq = tid & 31;
        float4 v = make_float4(0.f, 0.f, 0.f, 0.f);
        if (cq < 25) v = *(const float4*)&Zb[r * 100 + cq * 4];
        else if (cq == 25) v.x = dv[r];
        *(float4*)&zl[0][r * 128 + cq * 4] = v;
    }
    __syncthreads();

    int l = tid & 63, w = tid >> 6;
    int mtg = w >> 2, ntg = w & 3;
    int nmt = mtg ? 3 : 4;
    int mbase = mtg * 128;
    int cl = l & 31;
    int myc = ntg * 32 + cl;
    int kg = l >> 5;

    f32x16 acc0, acc1, acc2, acc3;
    #pragma unroll
    for (int i = 0; i < 16; i++) { acc0[i] = 0.f; acc1[i] = 0.f; acc2[i] = 0.f; acc3[i] = 0.f; }

    int cur = 0;
    for (int ks = 0; ks < 13; ks++) {
        // early-issue next-slab global loads
        float4 stg = make_float4(0.f, 0.f, 0.f, 0.f);
        int sr = tid >> 5, scq = tid & 31;
        bool do_stage = (ks < 12);
        if (do_stage) {
            int n = (ks + 1) * 16 + sr;
            if (n < 200) {
                if (scq < 25) stg = *(const float4*)&Zb[n * 100 + scq * 4];
                else if (scq == 25) stg.x = dv[n];
            }
        }

        // Z fragment (this wave's 32-col slice), split into 3 bf16 planes
        float zv[8];
        #pragma unroll
        for (int j = 0; j < 8; j++) zv[j] = zl[cur][(kg * 8 + j) * 128 + myc];
        bf16x8 zs0, zs1, zs2;
        zsplit_pack(zv, zs0, zs1, zs2);

        int wbase = (ks >> 1) * 208;
        int shmt = ((ks & 1) << 4) | (kg << 3);
        #pragma unroll
        for (int mt = 0; mt < 4; mt++) {
            if (mt < nmt) {
                int m = mbase + mt * 32 + cl;
                unsigned word = mkl[wbase + m];
                unsigned byte = (word >> shmt) & 0xFFu;
                bf16x8 af = afrag_bits(byte);
                f32x16* pa = (mt == 0) ? &acc0 : (mt == 1) ? &acc1 : (mt == 2) ? &acc2 : &acc3;
                *pa = __builtin_amdgcn_mfma_f32_32x32x16_bf16(af, zs0, *pa, 0, 0, 0);
                *pa = __builtin_amdgcn_mfma_f32_32x32x16_bf16(af, zs1, *pa, 0, 0, 0);
                *pa = __builtin_amdgcn_mfma_f32_32x32x16_bf16(af, zs2, *pa, 0, 0, 0);
            }
        }

        if (do_stage) *(float4*)&zl[cur ^ 1][sr * 128 + scq * 4] = stg;
        __syncthreads();
        cur ^= 1;
    }

    // store: D layout col=l&31, row=(r&3)+8*(r>>2)+4*(l>>5)   [m74/m101]
    float* Zob = Zout + bf * 20000;
    float* Dhb = Dh + bf * 200;
    #pragma unroll
    for (int mt = 0; mt < 4; mt++) {
        if (mt < nmt) {
            const f32x16& a = (mt == 0) ? acc0 : (mt == 1) ? acc1 : (mt == 2) ? acc2 : acc3;
            #pragma unroll
            for (int r = 0; r < 16; r++) {
                int m = mbase + mt * 32 + (r & 3) + ((r >> 2) << 3) + (kg << 2);
                if (m < 200) {
                    if (myc < 100) Zob[m * 100 + myc] = a[r];
                    else if (myc == 100) Dhb[m] = a[r];
                }
            }
        }
    }
}

// ---------------------------------------------------------------------------
// fp32 fallback GEMM (small out0 GEMM)
__global__ __launch_bounds__(256) void zh_gemm(
    const float* __restrict__ src, const float* __restrict__ wbase,
    const float* __restrict__ uni, const float* __restrict__ rowscale,
    float* __restrict__ dst, int src_head)
{
    int f = blockIdx.x, b = blockIdx.y;
    int NHg = gridDim.x;
    const float* W = wbase + (size_t)f * 10000;
    const float* S = src + (size_t)(src_head ? (b * NHg + f) : b) * 20000;
    float* Dst = dst + (size_t)(b * NHg + f) * 20000;

    __shared__ __align__(16) float wl[10000];
    __shared__ __align__(16) float xl[5000];

    int tid = threadIdx.x;
    for (int idx = tid; idx < 10000; idx += 256) wl[idx] = W[idx];
    float u = uni ? uni[b * NHEAD + f] : 1.0f;

    int q = tid % 25;
    int ty = tid / 25;

    for (int c = 0; c < 4; c++) {
        __syncthreads();
        int base = c * 5000;
        for (int idx = tid; idx < 5000; idx += 256) {
            int row = idx / 100;
            float sc = rowscale ? rowscale[b * NNODE + c * 50 + row] : 1.0f;
            xl[idx] = S[base + idx] * sc;
        }
        __syncthreads();
        if (ty < 10) {
            float4 acc[5];
            #pragma unroll
            for (int r = 0; r < 5; r++) acc[r] = make_float4(0.f, 0.f, 0.f, 0.f);
            #pragma unroll 2
            for (int i = 0; i < 100; i++) {
                float4 w4 = *(const float4*)&wl[i * 100 + q * 4];
                #pragma unroll
                for (int r = 0; r < 5; r++) {
                    float x = xl[(ty + 10 * r) * 100 + i];
                    acc[r].x += x * w4.x; acc[r].y += x * w4.y;
                    acc[r].z += x * w4.z; acc[r].w += x * w4.w;
                }
            }
            #pragma unroll
            for (int r = 0; r < 5; r++) {
                int n = c * 50 + ty + 10 * r;
                float4 o4 = make_float4(acc[r].x * u, acc[r].y * u, acc[r].z * u, acc[r].w * u);
                *(float4*)&Dst[n * 100 + q * 4] = o4;
            }
        }
    }
}

// ---------------------------------------------------------------------------
__global__ void dsum_rs(const float* __restrict__ Dh, const float* __restrict__ endat,
                        float* __restrict__ rs) {
    int idx = blockIdx.x * 256 + threadIdx.x;
    if (idx >= NBATCH * NNODE) return;
    int b = idx / NNODE, m = idx % NNODE;
    float s = 0.f;
    #pragma unroll
    for (int f = 0; f < NHEAD; f++) s += Dh[((size_t)b * NHEAD + f) * NNODE + m];
    float e = endat[idx];
    rs[idx] = e / (e * s + EPSV);
}

// ---------------------------------------------------------------------------
__global__ void dmix(const float* __restrict__ Dh0, const float* __restrict__ trans,
                     const float* __restrict__ uni, float* __restrict__ dvec1) {
    int b = blockIdx.x;
    __shared__ float tl[NHEAD * NHEAD];
    for (int idx = threadIdx.x; idx < NHEAD * NHEAD; idx += 256) tl[idx] = trans[b * NHEAD * NHEAD + idx];
    __syncthreads();
    int n = threadIdx.x;
    if (n < NNODE) {
        float dh[NHEAD];
        #pragma unroll
        for (int f = 0; f < NHEAD; f++) dh[f] = Dh0[((size_t)b * NHEAD + f) * NNODE + n];
        #pragma unroll
        for (int g = 0; g < NHEAD; g++) {
            float acc = 0.f;
            #pragma unroll
            for (int f = 0; f < NHEAD; f++) acc += dh[f] * tl[f * NHEAD + g];
            dvec1[((size_t)b * NHEAD + g) * NNODE + n] = uni[b * NHEAD + g] * acc;
        }
    }
}

// ---------------------------------------------------------------------------
__global__ __launch_bounds__(256) void hmix(
    const float* __restrict__ Zsrc, const float* __restrict__ trans,
    float* __restrict__ Zdst, float* __restrict__ Zsum)
{
    int b = blockIdx.y;
    int c = blockIdx.x * 256 + threadIdx.x;
    __shared__ __align__(8) float tl[NHEAD * NHEAD];
    for (int idx = threadIdx.x; idx < NHEAD * NHEAD; idx += 256) tl[idx] = trans[b * NHEAD * NHEAD + idx];
    __syncthreads();
    if (c >= 20000) return;
    const float* Zb = Zsrc + (size_t)b * NHEAD * 20000 + c;
    float acc[NHEAD];
    #pragma unroll
    for (int g = 0; g < NHEAD; g++) acc[g] = 0.f;
    float s = 0.f;
    for (int f = 0; f < NHEAD; f++) {
        float vf = Zb[(size_t)f * 20000];
        s += vf;
        const float2* row = (const float2*)&tl[f * NHEAD];
        #pragma unroll
        for (int gq = 0; gq < 17; gq++) {
            float2 t2 = row[gq];
            acc[2 * gq]     += vf * t2.x;
            acc[2 * gq + 1] += vf * t2.y;
        }
    }
    Zsum[(size_t)b * 20000 + c] = s;
    float* Zd = Zdst + (size_t)b * NHEAD * 20000 + c;
    #pragma unroll
    for (int g = 0; g < NHEAD; g++) Zd[(size_t)g * 20000] = acc[g];
}

// ---------------------------------------------------------------------------
__global__ void fsum_out(const float* __restrict__ Zacc, const float* __restrict__ rs,
                         float* __restrict__ out) {
    int idx = blockIdx.x * 256 + threadIdx.x;
    if (idx >= NBATCH * NNODE * HDIM) return;
    int b = idx / 20000;
    int c = idx % 20000;
    int n = c / 100;
    float s = 0.f;
    #pragma unroll
    for (int g = 0; g < NHEAD; g++) s += Zacc[((size_t)b * NHEAD + g) * 20000 + c];
    out[idx] = s * rs[b * NNODE + n];
}

// ---------------------------------------------------------------------------
extern "C" void kernel_launch(void* const* d_in, const int* in_sizes, int n_in,
                              void* d_out, int out_size, void* d_ws, size_t ws_size,
                              hipStream_t stream) {
    (void)in_sizes; (void)n_in;
    const float* X     = (const float*)d_in[0];
    const float* A     = (const float*)d_in[1];
    const float* start = (const float*)d_in[2];
    const float* endat = (const float*)d_in[3];
    const float* uni   = (const float*)d_in[4];
    const float* trans = (const float*)d_in[5];
    const float* wv    = (const float*)d_in[6];
    float* out = (float*)d_out;
    float* ws  = (float*)d_ws;

    size_t off = 0;
    unsigned long long* bm = (unsigned long long*)(ws); off += 1740800;
    float* buf1  = ws + off; off += 21760000;
    float* buf2  = ws + off; off += 21760000;
    float* dvec0 = ws + off; off += 217600;
    float* Dh0   = ws + off; off += 217600;
    float* dvec1 = ws + off; off += 217600;
    float* Dh1   = ws + off; off += 217600;
    float* rs0   = ws + off; off += 6400;
    float* rs1   = ws + off; off += 6400;
    float* Zsum0 = ws + off; off += 640000;
    short* wfr   = (short*)(ws + off); off += 1462272;
    short* xfr   = (short*)(ws + off); off += 1277952;
    if (ws_size < off * sizeof(float)) {
        hipMemsetAsync(d_out, 0x7F, (size_t)out_size * sizeof(float), stream);
        return;
    }

    const float* Wi1 = wv + 690000;
    const short* wfr0 = wfr;
    const short* wfr1 = wfr + (size_t)34 * 28 * 3 * 512;
    const unsigned* bm32 = (const unsigned*)bm;

    dim3 gBF(NHEAD, NBATCH);

    // prepasses
    a_bitmask<<<(NBATCH * NHEAD * NNODE + 15) / 16, 1024, 0, stream>>>(A, bm);
    wsplit<<<68, 256, 0, stream>>>(wv, wfr);
    asplit<<<32, 256, 0, stream>>>(X, start, xfr);
    dvec0_calc<<<(NBATCH * NHEAD * NNODE + 255) / 256, 256, 0, stream>>>(start, uni, dvec0);

    // t = 0
    mfma_zh<true><<<gBF, 256, 0, stream>>>(xfr, nullptr, wfr0, uni, buf1);    // buf1 = Zh0
    a_mfma<<<gBF, 512, 0, stream>>>(bm32, buf1, dvec0, buf2, Dh0);            // buf2 = AZh0
    dsum_rs<<<(NBATCH * NNODE + 255) / 256, 256, 0, stream>>>(Dh0, endat, rs0);
    dmix<<<NBATCH, 256, 0, stream>>>(Dh0, trans, uni, dvec1);
    hmix<<<dim3(79, NBATCH), 256, 0, stream>>>(buf2, trans, buf1, Zsum0);     // buf1 = Zin1
    zh_gemm<<<dim3(1, NBATCH), 256, 0, stream>>>(Zsum0, Wi1, nullptr, rs0, out, 0); // out[0]

    // t = 1
    mfma_zh<false><<<gBF, 256, 0, stream>>>(nullptr, buf1, wfr1, uni, buf2);  // buf2 = Zh1
    a_mfma<<<gBF, 512, 0, stream>>>(bm32, buf2, dvec1, buf1, Dh1);            // buf1 = AZh1
    dsum_rs<<<(NBATCH * NNODE + 255) / 256, 256, 0, stream>>>(Dh1, endat, rs1);
    fsum_out<<<(NBATCH * NNODE * HDIM + 255) / 256, 256, 0, stream>>>(buf1, rs1, out + 640000);
}